// Round 10
// baseline (162.656 us; speedup 1.0000x reference)
//
#include <hip/hip_runtime.h>
#include <hip/hip_bf16.h>
#include <math.h>

// ---------------------------------------------------------------------------
// LeNet-ish forward, MFMA convs + MFMA fc0 (bf16 act2, direct-global A-frags).
// Scratch inside d_out (float units):
//  [0)          act1 (bf16, rows padded to 256) 16*6*254*256 u16 = 3,121,152 f
//  [3,121,152)  act2 (bf16) 16*250000 u16 = 2,000,000 f
//  [5,121,152)  fc0 partials 489*1920 = 938,880
//  [6,060,032)  h0           1,920
// d_ws: params g1[16], g2[16], gain[16]
// ---------------------------------------------------------------------------

#define EPSF 1e-8f
typedef unsigned short ushort_t;
typedef __attribute__((ext_vector_type(8))) short short8;
typedef __attribute__((ext_vector_type(4))) float f32x4;

__device__ __forceinline__ float sigmf(float x) {
    return 1.0f / (1.0f + __expf(-x));
}
__device__ __forceinline__ unsigned short f2bf(float f) {
    unsigned int u = __float_as_uint(f);
    unsigned int r = (u + 0x7FFFu + ((u >> 16) & 1u)) >> 16;
    return (unsigned short)r;
}
// pack two floats to bf16x2 (round-half-up)
__device__ __forceinline__ unsigned pk2bf(float a, float b) {
    unsigned ua = __float_as_uint(a), ub = __float_as_uint(b);
    return ((ua + 0x8000u) >> 16) | ((ub + 0x8000u) & 0xFFFF0000u);
}

// ============================ conv1 (MFMA) =================================
// img (16,3,512,512) f32 -> act1 (16,6,254,[256]) bf16, sigmoid(maxpool+bias)
// Block (xc 0..3, yc 0..31, b): 8 pooled rows x 64 pooled x.
#define C1_ROWB 288
#define C1_P1   17296          // 60*288 + 16 pad (4-bank shift)

__global__ __launch_bounds__(256) void k_conv1(const float* __restrict__ img,
                                               const float* __restrict__ w,
                                               const float* __restrict__ bias,
                                               ushort_t* __restrict__ act1) {
    __shared__ unsigned char sh[C1_P1 + 60 * C1_ROWB];   // 34576 B
    const int tid = threadIdx.x;
    const int xc = blockIdx.x, yc = blockIdx.y, b = blockIdx.z;
    const int x0c = xc * 128;

    for (int i = tid; i < 2160; i += 256) {
        int plane = i / 720;
        int r20 = (i / 36) % 20;
        int c4 = i % 36;
        int gr = 16 * yc + r20;
        int gx = x0c + c4 * 4;
        float v0 = 0.f, v1 = 0.f, v2 = 0.f, v3 = 0.f, v4 = 0.f;
        if (gr < 512 && gx < 512) {
            const float* ip = img + ((size_t)(b * 3 + plane) * 512 + gr) * 512;
            float4 t = *(const float4*)(ip + gx);
            v0 = t.x; v1 = t.y; v2 = t.z; v3 = t.w;
            if (gx + 4 < 512) v4 = ip[gx + 4];
        }
        unsigned bofs = (unsigned)((plane * 20 + r20) * C1_ROWB + c4 * 8);
        *(uint2*)(sh + bofs) = make_uint2(pk2bf(v0, v1), pk2bf(v2, v3));
        *(uint2*)(sh + C1_P1 + bofs) = make_uint2(pk2bf(v1, v2), pk2bf(v3, v4));
    }

    const int lane = tid & 63;
    const int g = lane >> 4;
    const int m = lane & 15;
    const int par = m & 1;
    const int mh = m >> 1;
    const int p = mh & 1;

    const int ocw = (m < 6) ? m : 0;
    short8 fb[4];
#pragma unroll
    for (int s = 0; s < 4; ++s) {
        int t = 4 * s + g;
        unsigned u0 = 0, u1 = 0, u2 = 0;
        if (t < 15 && m < 6) {
            int ic = t / 5, ky = t % 5;
            const float* wp = w + ((ocw * 4 + ic) * 5 + ky) * 5;
            const float* w3 = w + ((ocw * 4 + 3) * 5 + ky) * 5;
            float a0 = wp[0] + w3[0] * (1.f / 3.f);
            float a1 = wp[1] + w3[1] * (1.f / 3.f);
            float a2 = wp[2] + w3[2] * (1.f / 3.f);
            float a3 = wp[3] + w3[3] * (1.f / 3.f);
            float a4 = wp[4] + w3[4] * (1.f / 3.f);
            u0 = pk2bf(a0, a1);
            u1 = pk2bf(a2, a3);
            u2 = pk2bf(a4, 0.f);
        }
        union { unsigned u[4]; short8 v; } uu;
        uu.u[0] = u0; uu.u[1] = u1; uu.u[2] = u2; uu.u[3] = 0;
        fb[s] = uu.v;
    }
    unsigned offv[4];
#pragma unroll
    for (int s = 0; s < 4; ++s) {
        int t = 4 * s + g;
        offv[s] = (t < 15) ? (unsigned)(((t / 5) * 20 + (t % 5)) * C1_ROWB) : 0u;
    }
    const float bv = (m < 6) ? bias[m] : 0.f;
    __syncthreads();

    const int wv = tid >> 6;
    const unsigned laneoff = (p ? C1_P1 : 0u) + (unsigned)(par * C1_ROWB)
                             + (unsigned)((mh & ~1) * 2) + (unsigned)(wv * 16);
    ushort_t* sb = act1 + ((size_t)(b * 6 + ocw) * 254 + 8 * yc) * 256
                   + (x0c >> 1) + wv * 4 + g;
    const bool mok = (m < 6);
    const int YPb = 8 * yc;
    const int xlim = 508 - 2 * g - 1;

#pragma unroll
    for (int rp = 0; rp < 8; ++rp) {
#pragma unroll
        for (int xtq = 0; xtq < 4; ++xtq) {
            const unsigned char* base = sh + laneoff + rp * (2 * C1_ROWB) + xtq * 128;
            f32x4 acc = {0.f, 0.f, 0.f, 0.f};
#pragma unroll
            for (int s = 0; s < 4; ++s) {
                const unsigned* q = (const unsigned*)(base + offv[s]);
                union { unsigned u[4]; short8 v; } ua;
                ua.u[0] = q[0]; ua.u[1] = q[1]; ua.u[2] = q[2]; ua.u[3] = q[3];
                acc = __builtin_amdgcn_mfma_f32_16x16x32_bf16(ua.v, fb[s], acc, 0, 0, 0);
            }
            int xt = xtq * 4 + wv;
            int x0 = x0c + xt * 8;
            if (mok && (YPb + rp) < 254 && x0 < xlim) {
                float mx = fmaxf(fmaxf(acc[0], acc[1]), fmaxf(acc[2], acc[3])) + bv;
                sb[rp * 256 + xtq * 16] = f2bf(sigmf(mx));
            }
        }
    }
}

// ============================ conv2 (MFMA) =================================
// act1 (16,6,254,[256]) bf16 -> act2 (16,16,125,125) bf16
#define C2_ROWB 288
#define C2_P1   20752          // 72*288 + 16 pad

__global__ __launch_bounds__(256) void k_conv2(const ushort_t* __restrict__ act1,
                                               const float* __restrict__ w,
                                               const float* __restrict__ bias,
                                               ushort_t* __restrict__ act2) {
    __shared__ unsigned char sh[C2_P1 + 72 * C2_ROWB];   // 41488 B
    const int tid = threadIdx.x;
    const int xc = blockIdx.x, yc = blockIdx.y, b = blockIdx.z;
    const int x0c = xc * 128;

    for (int i = tid; i < 2592; i += 256) {
        int plane = i / 432;
        int r12 = (i / 36) % 12;
        int c4 = i % 36;
        int gr = 8 * yc + r12;
        int gx = x0c + c4 * 4;
        unsigned d0 = 0, d1 = 0, h4 = 0;
        if (gr < 254 && gx + 3 < 256) {
            const ushort_t* ip = act1 + ((size_t)(b * 6 + plane) * 254 + gr) * 256;
            uint2 t = *(const uint2*)(ip + gx);
            d0 = t.x; d1 = t.y;
            if (gx + 4 < 256) h4 = ip[gx + 4];
        }
        unsigned bofs = (unsigned)((plane * 12 + r12) * C2_ROWB + c4 * 8);
        *(uint2*)(sh + bofs) = make_uint2(d0, d1);
        unsigned e0 = (d0 >> 16) | (d1 << 16);
        unsigned e1 = (d1 >> 16) | (h4 << 16);
        *(uint2*)(sh + C2_P1 + bofs) = make_uint2(e0, e1);
    }

    const int lane = tid & 63;
    const int g = lane >> 4;
    const int m = lane & 15;     // oc
    const int par = m & 1;
    const int mh = m >> 1;
    const int p = mh & 1;

    short8 fb[8];
#pragma unroll
    for (int s = 0; s < 8; ++s) {
        int t = 4 * s + g;
        unsigned u0 = 0, u1 = 0, u2 = 0;
        if (t < 30) {
            int ic = t / 5, ky = t % 5;
            const float* wp = w + ((m * 6 + ic) * 5 + ky) * 5;
            u0 = pk2bf(wp[0], wp[1]);
            u1 = pk2bf(wp[2], wp[3]);
            u2 = pk2bf(wp[4], 0.f);
        }
        union { unsigned u[4]; short8 v; } uu;
        uu.u[0] = u0; uu.u[1] = u1; uu.u[2] = u2; uu.u[3] = 0;
        fb[s] = uu.v;
    }
    unsigned offv[8];
#pragma unroll
    for (int s = 0; s < 8; ++s) {
        int t = 4 * s + g;
        offv[s] = (t < 30) ? (unsigned)(((t / 5) * 12 + (t % 5)) * C2_ROWB) : 0u;
    }
    const float bv = bias[m];
    __syncthreads();

    const int wv = tid >> 6;
    const unsigned laneoff = (p ? C2_P1 : 0u) + (unsigned)(par * C2_ROWB)
                             + (unsigned)((mh & ~1) * 2) + (unsigned)(wv * 16);
    // act2 flat per batch: k = oc*15625 + yp*125 + xp
    ushort_t* sb = act2 + (size_t)b * 250000 + (size_t)m * 15625
                   + (size_t)(4 * yc) * 125 + (x0c >> 1) + wv * 4 + g;
    const int YPb = 4 * yc;
    const int xlim = 250 - 2 * g - 1;

#pragma unroll
    for (int rp = 0; rp < 4; ++rp) {
#pragma unroll
        for (int xtq = 0; xtq < 4; ++xtq) {
            const unsigned char* base = sh + laneoff + rp * (2 * C2_ROWB) + xtq * 128;
            f32x4 acc = {0.f, 0.f, 0.f, 0.f};
#pragma unroll
            for (int s = 0; s < 8; ++s) {
                const unsigned* q = (const unsigned*)(base + offv[s]);
                union { unsigned u[4]; short8 v; } ua;
                ua.u[0] = q[0]; ua.u[1] = q[1]; ua.u[2] = q[2]; ua.u[3] = q[3];
                acc = __builtin_amdgcn_mfma_f32_16x16x32_bf16(ua.v, fb[s], acc, 0, 0, 0);
            }
            int xt = xtq * 4 + wv;
            int x0 = x0c + xt * 8;
            if ((YPb + rp) < 125 && x0 < xlim) {
                float mx = fmaxf(fmaxf(acc[0], acc[1]), fmaxf(acc[2], acc[3])) + bv;
                sb[rp * 125 + xtq * 16] = f2bf(sigmf(mx));
            }
        }
    }
}

// ---------------- fc0 partials (MFMA GEMM, direct-global bf16 A) ----------
// y[16b][120o] = X(16,250000)bf16 . W^T, K over 489 blocks of 512.
// Block = 4 waves; wave k-span 128. A-frags loaded once per block directly
// from global act2 (16B aligned, L3-resident); no X staging, no swizzle.
#define FC0_KBLK 512
#define FC0_NB   489

__global__ __launch_bounds__(256) void k_fc0(const ushort_t* __restrict__ x,
                                             const float* __restrict__ w,
                                             float* __restrict__ partial) {
    __shared__ float sY[4][128][17];
    const int tid = threadIdx.x;
    const int blk = blockIdx.x;
    const int k0 = blk * FC0_KBLK;
    const int valid = min(FC0_KBLK, 250000 - k0);

    const int wv = tid >> 6, lane = tid & 63;
    const int g = lane >> 4, m = lane & 15;
    const int kw = wv * 128;

    // A-frags: X[row=batch m][k0 + kw + s*32 + g*8 .. +7]; zero past tail
    short8 fa[4];
#pragma unroll
    for (int s = 0; s < 4; ++s) {
        int kc = kw + s * 32 + g * 8;
        union { unsigned u[4]; short8 v; } uz;
        uz.u[0] = uz.u[1] = uz.u[2] = uz.u[3] = 0;
        fa[s] = (kc < valid)
              ? *(const short8*)(x + (size_t)m * 250000 + k0 + kc)
              : uz.v;
    }

    const int kwmax = (250000 - k0) - 4;

#pragma unroll 2
    for (int nt = 0; nt < 8; ++nt) {
        const int o0 = nt * 16;
        const int orow = min(o0 + m, 119);
        const float* wr = w + (size_t)orow * 250000 + k0;
        f32x4 acc = {0.f, 0.f, 0.f, 0.f};
#pragma unroll
        for (int s = 0; s < 4; ++s) {
            int kc = kw + s * 32 + g * 8;
            int ka = (kc < kwmax) ? kc : kwmax;
            int kb = (kc + 4 < kwmax) ? kc + 4 : kwmax;
            float4 w0 = *(const float4*)(wr + ka);
            float4 w1 = *(const float4*)(wr + kb);
            union { unsigned u[4]; short8 v; } ub;
            ub.u[0] = pk2bf(w0.x, w0.y);
            ub.u[1] = pk2bf(w0.z, w0.w);
            ub.u[2] = pk2bf(w1.x, w1.y);
            ub.u[3] = pk2bf(w1.z, w1.w);
            acc = __builtin_amdgcn_mfma_f32_16x16x32_bf16(fa[s], ub.v, acc, 0, 0, 0);
        }
#pragma unroll
        for (int i = 0; i < 4; ++i) sY[wv][o0 + m][g * 4 + i] = acc[i];
    }
    __syncthreads();

    float* pp = partial + (size_t)blk * 1920;
    for (int i = tid; i < 1920; i += 256) {
        int o = i >> 4, b = i & 15;
        pp[i] = sY[0][o][b] + sY[1][o][b] + sY[2][o][b] + sY[3][o][b];
    }
}

// ---------------- fc0 reduce + bias + sigmoid ----------------
__global__ __launch_bounds__(256) void k_fc0red(const float* __restrict__ partial,
                                                const float* __restrict__ b0,
                                                float* __restrict__ h0) {
    const int tid = threadIdx.x;
    const int wv = tid >> 6, l = tid & 63;
    const int i = blockIdx.x * 4 + wv;
    float s = 0.0f;
    for (int c = l; c < FC0_NB; c += 64) s += partial[(size_t)c * 1920 + i];
    s += __shfl_xor(s, 1);
    s += __shfl_xor(s, 2);
    s += __shfl_xor(s, 4);
    s += __shfl_xor(s, 8);
    s += __shfl_xor(s, 16);
    s += __shfl_xor(s, 32);
    if (l == 0) {
        int o = i >> 4, bb = i & 15;
        h0[bb * 120 + o] = sigmf(s + b0[o]);
    }
}

__global__ __launch_bounds__(256) void k_fctail(const float* __restrict__ h0in,
                                                const float* __restrict__ fc1_w,
                                                const float* __restrict__ fc1_b,
                                                const float* __restrict__ fc2_w,
                                                const float* __restrict__ fc2_b,
                                                const float* __restrict__ gb1,
                                                const float* __restrict__ gb2,
                                                const float* __restrict__ base1,
                                                float* __restrict__ params) {
    __shared__ float sh0[1920];
    __shared__ float sh1[16][84];
    __shared__ float sout[16][10];
    const int tid = threadIdx.x;

    for (int i = tid; i < 1920; i += 256) sh0[i] = h0in[i];
    __syncthreads();

    for (int i = tid; i < 16 * 84; i += 256) {
        int bb = i / 84, o = i % 84;
        float a = fc1_b[o];
        for (int k = 0; k < 120; ++k) a = fmaf(sh0[bb * 120 + k], fc1_w[o * 120 + k], a);
        sh1[bb][o] = sigmf(a);
    }
    __syncthreads();

    for (int i = tid; i < 160; i += 256) {
        int bb = i / 10, o = i % 10;
        float a = fc2_b[o];
        for (int k = 0; k < 84; ++k) a = fmaf(sh1[bb][k], fc2_w[o * 84 + k], a);
        sout[bb][o] = a;
    }
    __syncthreads();

    if (tid < 16) {
        int bb = tid;
        float g1 = sout[bb][0] + gb1[0];
        float g2 = sout[bb][1] + gb2[0];
        float gain = 0.0f;
        for (int j = 0; j < 8; ++j) gain += sout[bb][2 + j] + base1[j];
        params[bb] = g1;
        params[16 + bb] = g2;
        params[32 + bb] = gain;
    }
}

__global__ __launch_bounds__(256) void k_final(const float* __restrict__ img,
                                               const float* __restrict__ params,
                                               float* __restrict__ out) {
    int idx = blockIdx.x * 256 + threadIdx.x;
    int p = idx * 4;
    int b = p >> 18;
    int hw = p & 262143;
    size_t base = ((size_t)b * 3) * 262144 + hw;

    float4 r = *(const float4*)(img + base);
    float4 g = *(const float4*)(img + base + 262144);
    float4 bl = *(const float4*)(img + base + 2 * 262144);
    float g1 = params[b], g2 = params[16 + b], gain = params[32 + b];

    float4 o0, o1, o2;
#pragma unroll
    for (int e = 0; e < 4; ++e) {
        float re = (&r.x)[e], ge = (&g.x)[e], be = (&bl.x)[e];
        float I = (re + ge + be) * (1.0f / 3.0f);
        float gv = (I > 0.5f) ? g2 : g1;
        (&o0.x)[e] = __powf(fminf(fmaxf(re * gain, EPSF), 1.0f), gv);
        (&o1.x)[e] = __powf(fminf(fmaxf(ge * gain, EPSF), 1.0f), gv);
        (&o2.x)[e] = __powf(fminf(fmaxf(be * gain, EPSF), 1.0f), gv);
    }
    *(float4*)(out + base) = o0;
    *(float4*)(out + base + 262144) = o1;
    *(float4*)(out + base + 2 * 262144) = o2;
}

// ---------------------------------------------------------------------------
extern "C" void kernel_launch(void* const* d_in, const int* in_sizes, int n_in,
                              void* d_out, int out_size, void* d_ws, size_t ws_size,
                              hipStream_t stream) {
    const float* img     = (const float*)d_in[0];
    const float* conv1_w = (const float*)d_in[1];
    const float* conv1_b = (const float*)d_in[2];
    const float* conv2_w = (const float*)d_in[3];
    const float* conv2_b = (const float*)d_in[4];
    const float* fc0_w   = (const float*)d_in[5];
    const float* fc0_b   = (const float*)d_in[6];
    const float* fc1_w   = (const float*)d_in[7];
    const float* fc1_b   = (const float*)d_in[8];
    const float* fc2_w   = (const float*)d_in[9];
    const float* fc2_b   = (const float*)d_in[10];
    const float* gb1     = (const float*)d_in[11];
    const float* gb2     = (const float*)d_in[12];
    const float* base1   = (const float*)d_in[13];

    float* outp = (float*)d_out;
    ushort_t* act1  = (ushort_t*)outp;              // 16*6*254*256 bf16
    ushort_t* act2b = (ushort_t*)(outp + 3121152);  // 16*250000 bf16
    float* partial  = outp + 5121152;               // 938,880
    float* h0       = outp + 6060032;               // 1,920
    float* params   = (float*)d_ws;                 // 48 floats

    k_conv1<<<dim3(4, 32, 16), dim3(256), 0, stream>>>(img, conv1_w, conv1_b, act1);
    k_conv2<<<dim3(2, 32, 16), dim3(256), 0, stream>>>(act1, conv2_w, conv2_b, act2b);
    k_fc0<<<dim3(FC0_NB), dim3(256), 0, stream>>>(act2b, fc0_w, partial);
    k_fc0red<<<dim3(480), dim3(256), 0, stream>>>(partial, fc0_b, h0);
    k_fctail<<<dim3(1), dim3(256), 0, stream>>>(h0, fc1_w, fc1_b, fc2_w, fc2_b,
                                                gb1, gb2, base1, params);
    k_final<<<dim3(4096), dim3(256), 0, stream>>>(img, params, outp);
}